// Round 1
// baseline (256.796 us; speedup 1.0000x reference)
//
#include <hip/hip_runtime.h>
#include <hip/hip_bf16.h>

#define B_ 2
#define N_ 2048
#define C_ 1024
#define H_ 16
#define D_ 64
#define HALF_ 32

typedef __attribute__((ext_vector_type(8))) __bf16 bf16x8;
typedef __attribute__((ext_vector_type(8))) unsigned short u16x8;
typedef __attribute__((ext_vector_type(4))) float f32x4;

__device__ __forceinline__ unsigned short f2bf(float f) {
  union { float f; unsigned u; } v; v.f = f;
  unsigned r = v.u + 0x7FFFu + ((v.u >> 16) & 1u);
  return (unsigned short)(r >> 16);
}

// ---------------- cast f32 -> bf16 (vectorized x4) ----------------
__global__ __launch_bounds__(256) void cast_f32_bf16(const float* __restrict__ in,
                                                     unsigned short* __restrict__ out,
                                                     int n4) {
  int i = blockIdx.x * 256 + threadIdx.x;
  if (i >= n4) return;
  float4 v = reinterpret_cast<const float4*>(in)[i];
  ushort4 o;
  o.x = f2bf(v.x); o.y = f2bf(v.y); o.z = f2bf(v.z); o.w = f2bf(v.w);
  reinterpret_cast<ushort4*>(out)[i] = o;
}

// ---------------- GEMM C[M][N] = A[M][K] * Bw[N][K]^T ----------------
// EPI==0: f32 out + bias (proj).  EPI==1: fused RoPE + split q/k/v bf16 (qkv).
template <int EPI>
__global__ __launch_bounds__(256) void gemm_bt(
    const unsigned short* __restrict__ A, const unsigned short* __restrict__ Bw,
    int M, int Nn, int K,
    float* __restrict__ Cout, const float* __restrict__ bias,
    unsigned short* __restrict__ qo, unsigned short* __restrict__ ko,
    unsigned short* __restrict__ vo,
    const float* __restrict__ cosT, const float* __restrict__ sinT) {
  __shared__ __align__(16) unsigned short As[128][72];
  __shared__ __align__(16) unsigned short Bs[128][72];
  const int tid = threadIdx.x;
  const int lane = tid & 63;
  const int wid = tid >> 6;
  const int wm = wid >> 1, wn = wid & 1;
  const int l15 = lane & 15;
  const int g = lane >> 4;
  const int m0 = blockIdx.x * 128;
  const int n0 = blockIdx.y * 128;

  f32x4 acc[4][4] = {};

  const int nK = K >> 6;
  for (int kt = 0; kt < nK; ++kt) {
    __syncthreads();
#pragma unroll
    for (int i = 0; i < 4; ++i) {
      int idx = tid + i * 256;          // 0..1023 : 128 rows x 8 chunks
      int row = idx >> 3, c8 = (idx & 7) << 3;
      *reinterpret_cast<u16x8*>(&As[row][c8]) =
          *reinterpret_cast<const u16x8*>(&A[(size_t)(m0 + row) * K + kt * 64 + c8]);
      *reinterpret_cast<u16x8*>(&Bs[row][c8]) =
          *reinterpret_cast<const u16x8*>(&Bw[(size_t)(n0 + row) * K + kt * 64 + c8]);
    }
    __syncthreads();
#pragma unroll
    for (int kk = 0; kk < 2; ++kk) {
      bf16x8 af[4], bfv[4];
#pragma unroll
      for (int m = 0; m < 4; ++m)
        af[m] = *reinterpret_cast<const bf16x8*>(&As[wm * 64 + m * 16 + l15][kk * 32 + g * 8]);
#pragma unroll
      for (int n = 0; n < 4; ++n)
        bfv[n] = *reinterpret_cast<const bf16x8*>(&Bs[wn * 64 + n * 16 + l15][kk * 32 + g * 8]);
#pragma unroll
      for (int m = 0; m < 4; ++m)
#pragma unroll
        for (int n = 0; n < 4; ++n)
          acc[m][n] = __builtin_amdgcn_mfma_f32_16x16x32_bf16(af[m], bfv[n], acc[m][n], 0, 0, 0);
    }
  }

  if constexpr (EPI == 0) {
#pragma unroll
    for (int n = 0; n < 4; ++n) {
      int col = n0 + wn * 64 + n * 16 + l15;
      float bv = bias[col];
#pragma unroll
      for (int m = 0; m < 4; ++m) {
        int rbase = m0 + wm * 64 + m * 16 + g * 4;
#pragma unroll
        for (int r = 0; r < 4; ++r)
          Cout[(size_t)(rbase + r) * Nn + col] = acc[m][n][r] + bv;
      }
    }
  } else {
    // RoPE + split epilogue. col -> (which, h, d); pair partner is lane^1.
#pragma unroll
    for (int m = 0; m < 4; ++m)
#pragma unroll
      for (int n = 0; n < 4; ++n)
#pragma unroll
        for (int r = 0; r < 4; ++r) {
          int col = n0 + wn * 64 + n * 16 + l15;
          int row = m0 + wm * 64 + m * 16 + g * 4 + r;
          float val = acc[m][n][r];
          float partner = __shfl_xor(val, 1);  // all lanes execute
          int which = col >> 10;
          int hc = col & 1023;
          int h = hc >> 6, d = hc & 63;
          int seq = row & (N_ - 1), bb = row >> 11;
          float res;
          if (which == 2) {
            res = val;
          } else {
            float cs = cosT[seq * HALF_ + (d >> 1)];
            float sn = sinT[seq * HALF_ + (d >> 1)];
            // even d: re' = re*c - im*s ; odd d: im' = re*s + im*c
            res = (d & 1) ? (partner * sn + val * cs) : (val * cs - partner * sn);
            if (which == 0) res *= 0.125f;  // fold scale = D^-0.5 into q
          }
          unsigned short* dst = (which == 0) ? qo : ((which == 1) ? ko : vo);
          dst[(((size_t)bb * H_ + h) * N_ + seq) * D_ + d] = f2bf(res);
        }
  }
}

// ---------------- flash attention, per (b,h), 4 waves x 16 q-rows ----------------
__global__ __launch_bounds__(256) void attn_kernel(
    const unsigned short* __restrict__ q,  // [B*H][N][D] bf16, q pre-scaled
    const unsigned short* __restrict__ k,
    const unsigned short* __restrict__ v,
    unsigned short* __restrict__ o) {      // [B*N][C] bf16
  __shared__ __align__(16) unsigned short Kl[64][72];
  __shared__ __align__(16) unsigned short Vt[64][72];   // transposed: [d][kv]
  __shared__ __align__(16) unsigned short Pl[4][16][72];

  const int tid = threadIdx.x;
  const int lane = tid & 63;
  const int w = tid >> 6;
  const int l15 = lane & 15;
  const int g = lane >> 4;
  const int qt = blockIdx.x;   // 0..31
  const int bh = blockIdx.y;   // 0..31
  const int b = bh >> 4, h = bh & 15;

  const size_t head_off = (size_t)bh * N_ * D_;
  const int qrow0 = qt * 64 + w * 16;

  bf16x8 qf[2];
#pragma unroll
  for (int kk = 0; kk < 2; ++kk)
    qf[kk] = *reinterpret_cast<const bf16x8*>(
        &q[head_off + (size_t)(qrow0 + l15) * D_ + kk * 32 + g * 8]);

  f32x4 accO[4] = {};
  float mrun[4], lrun[4];
#pragma unroll
  for (int r = 0; r < 4; ++r) { mrun[r] = -1e30f; lrun[r] = 0.f; }

  for (int t = 0; t < N_ / 64; ++t) {
    __syncthreads();
    // stage K [kv][d] and V transposed [d][kv]
#pragma unroll
    for (int i = 0; i < 2; ++i) {
      int idx = tid + i * 256;  // 0..511 : 64 rows x 8 chunks
      int row = idx >> 3, c8 = (idx & 7) << 3;
      *reinterpret_cast<u16x8*>(&Kl[row][c8]) =
          *reinterpret_cast<const u16x8*>(&k[head_off + (size_t)(t * 64 + row) * D_ + c8]);
      u16x8 vv = *reinterpret_cast<const u16x8*>(&v[head_off + (size_t)(t * 64 + row) * D_ + c8]);
#pragma unroll
      for (int j = 0; j < 8; ++j) Vt[c8 + j][row] = vv[j];
    }
    __syncthreads();

    // S = Q * K^T  (16 x 64 per wave)
    f32x4 sf[4];
#pragma unroll
    for (int f = 0; f < 4; ++f) {
      f32x4 z = {0.f, 0.f, 0.f, 0.f};
      sf[f] = z;
#pragma unroll
      for (int kk = 0; kk < 2; ++kk) {
        bf16x8 kb = *reinterpret_cast<const bf16x8*>(&Kl[f * 16 + l15][kk * 32 + g * 8]);
        sf[f] = __builtin_amdgcn_mfma_f32_16x16x32_bf16(qf[kk], kb, sf[f], 0, 0, 0);
      }
    }

    // online softmax (rows r live in lane group g; cols across l15)
    float fac[4];
#pragma unroll
    for (int r = 0; r < 4; ++r) {
      float mx = fmaxf(fmaxf(sf[0][r], sf[1][r]), fmaxf(sf[2][r], sf[3][r]));
      mx = fmaxf(mx, __shfl_xor(mx, 1));
      mx = fmaxf(mx, __shfl_xor(mx, 2));
      mx = fmaxf(mx, __shfl_xor(mx, 4));
      mx = fmaxf(mx, __shfl_xor(mx, 8));
      float mnew = fmaxf(mrun[r], mx);
      fac[r] = __expf(mrun[r] - mnew);
      mrun[r] = mnew;
      float s = 0.f;
#pragma unroll
      for (int f = 0; f < 4; ++f) {
        float p = __expf(sf[f][r] - mnew);
        sf[f][r] = p;
        s += p;
      }
      s += __shfl_xor(s, 1); s += __shfl_xor(s, 2);
      s += __shfl_xor(s, 4); s += __shfl_xor(s, 8);
      lrun[r] = lrun[r] * fac[r] + s;
    }

    // P -> wave-private LDS (to reach A-fragment layout)
#pragma unroll
    for (int f = 0; f < 4; ++f)
#pragma unroll
      for (int r = 0; r < 4; ++r)
        Pl[w][g * 4 + r][f * 16 + l15] = f2bf(sf[f][r]);
    asm volatile("s_waitcnt lgkmcnt(0)" ::: "memory");

    // rescale O
#pragma unroll
    for (int n = 0; n < 4; ++n)
#pragma unroll
      for (int r = 0; r < 4; ++r) accO[n][r] *= fac[r];

    // O += P * V
    bf16x8 pa[2];
#pragma unroll
    for (int kk = 0; kk < 2; ++kk)
      pa[kk] = *reinterpret_cast<const bf16x8*>(&Pl[w][l15][kk * 32 + g * 8]);
#pragma unroll
    for (int n = 0; n < 4; ++n)
#pragma unroll
      for (int kk = 0; kk < 2; ++kk) {
        bf16x8 vb = *reinterpret_cast<const bf16x8*>(&Vt[n * 16 + l15][kk * 32 + g * 8]);
        accO[n] = __builtin_amdgcn_mfma_f32_16x16x32_bf16(pa[kk], vb, accO[n], 0, 0, 0);
      }
  }

  // epilogue: normalize and store to [b][seq][h*64+d] bf16
#pragma unroll
  for (int n = 0; n < 4; ++n)
#pragma unroll
    for (int r = 0; r < 4; ++r) {
      int qrow = qrow0 + g * 4 + r;
      float val = accO[n][r] / lrun[r];
      o[((size_t)b * N_ + qrow) * C_ + h * 64 + n * 16 + l15] = f2bf(val);
    }
}

extern "C" void kernel_launch(void* const* d_in, const int* in_sizes, int n_in,
                              void* d_out, int out_size, void* d_ws, size_t ws_size,
                              hipStream_t stream) {
  const float* x      = (const float*)d_in[0];
  const float* qkv_w  = (const float*)d_in[1];
  const float* proj_w = (const float*)d_in[2];
  const float* proj_b = (const float*)d_in[3];
  const float* cosT   = (const float*)d_in[4];
  const float* sinT   = (const float*)d_in[5];
  float* out = (float*)d_out;

  // workspace layout (ushort elements), all 16B aligned
  unsigned short* xb     = (unsigned short*)d_ws;                 // 4096*1024
  unsigned short* wqkvb  = xb + (size_t)4096 * 1024;              // 3072*1024
  unsigned short* wprojb = wqkvb + (size_t)3072 * 1024;           // 1024*1024
  unsigned short* qb     = wprojb + (size_t)1024 * 1024;          // 32*2048*64
  unsigned short* kb     = qb + (size_t)32 * 2048 * 64;
  unsigned short* vb     = kb + (size_t)32 * 2048 * 64;
  unsigned short* ab     = vb + (size_t)32 * 2048 * 64;           // 4096*1024
  // total = 36 MB

  cast_f32_bf16<<<4096, 256, 0, stream>>>(x, xb, 4096 * 1024 / 4);
  cast_f32_bf16<<<3072, 256, 0, stream>>>(qkv_w, wqkvb, 3072 * 1024 / 4);
  cast_f32_bf16<<<1024, 256, 0, stream>>>(proj_w, wprojb, 1024 * 1024 / 4);

  dim3 g1(4096 / 128, 3072 / 128);
  gemm_bt<1><<<g1, 256, 0, stream>>>(xb, wqkvb, 4096, 3072, 1024,
                                     nullptr, nullptr, qb, kb, vb, cosT, sinT);

  dim3 g2(N_ / 64, B_ * H_);
  attn_kernel<<<g2, 256, 0, stream>>>(qb, kb, vb, ab);

  dim3 g3(4096 / 128, 1024 / 128);
  gemm_bt<0><<<g3, 256, 0, stream>>>(ab, wprojb, 4096, 1024, 1024,
                                     out, proj_b, nullptr, nullptr, nullptr,
                                     nullptr, nullptr);
}

// Round 2
// 216.414 us; speedup vs baseline: 1.1866x; 1.1866x over previous
//
#include <hip/hip_runtime.h>
#include <hip/hip_bf16.h>

#define B_ 2
#define N_ 2048
#define C_ 1024
#define H_ 16
#define D_ 64
#define HALF_ 32

typedef __attribute__((ext_vector_type(8))) __bf16 bf16x8;
typedef __attribute__((ext_vector_type(8))) unsigned short u16x8;
typedef __attribute__((ext_vector_type(4))) float f32x4;

__device__ __forceinline__ unsigned short f2bf(float f) {
  union { float f; unsigned u; } v; v.f = f;
  unsigned r = v.u + 0x7FFFu + ((v.u >> 16) & 1u);
  return (unsigned short)(r >> 16);
}

__device__ __forceinline__ void gload_lds16(const void* g, void* l) {
  __builtin_amdgcn_global_load_lds(
      (const __attribute__((address_space(1))) void*)g,
      (__attribute__((address_space(3))) void*)l, 16, 0, 0);
}

// ---------------- cast f32 -> bf16 (vectorized x4) ----------------
__global__ __launch_bounds__(256) void cast_f32_bf16(const float* __restrict__ in,
                                                     unsigned short* __restrict__ out,
                                                     int n4) {
  int i = blockIdx.x * 256 + threadIdx.x;
  if (i >= n4) return;
  float4 v = reinterpret_cast<const float4*>(in)[i];
  ushort4 o;
  o.x = f2bf(v.x); o.y = f2bf(v.y); o.z = f2bf(v.z); o.w = f2bf(v.w);
  reinterpret_cast<ushort4*>(out)[i] = o;
}

// ---------------- GEMM C[M][N] = A[M][K] * Bw[N][K]^T  (m97 structure) -------
// EPI==0: f32 out + bias (proj).  EPI==1: fused RoPE + split q/k/v^T bf16 (qkv).
template <int EPI>
__global__ __launch_bounds__(256) void gemm_bt(
    const unsigned short* __restrict__ A, const unsigned short* __restrict__ Bw,
    int M, int Nn, int K,
    float* __restrict__ Cout, const float* __restrict__ bias,
    unsigned short* __restrict__ qo, unsigned short* __restrict__ ko,
    unsigned short* __restrict__ vto,
    const float* __restrict__ cosT, const float* __restrict__ sinT) {
  __shared__ __align__(16) unsigned short As[128][64];
  __shared__ __align__(16) unsigned short Bs[128][64];
  const int tid = threadIdx.x;
  const int lane = tid & 63;
  const int wid = tid >> 6;
  const int wm = wid >> 1, wn = wid & 1;
  const int l15 = lane & 15;
  const int g = lane >> 4;
  const int m0 = blockIdx.x * 128;
  const int n0 = blockIdx.y * 128;

  const int srow = wid * 8 + (lane >> 3);   // row within a 32-row issue group
  const int scol = (lane & 7) * 8;          // shorts

  f32x4 acc[4][4] = {};

  const int nK = K >> 6;
  for (int kt = 0; kt < nK; ++kt) {
    __syncthreads();
#pragma unroll
    for (int j = 0; j < 4; ++j) {
      gload_lds16(&A[(size_t)(m0 + j * 32 + srow) * K + kt * 64 + scol],
                  &As[j * 32 + wid * 8][0]);
      gload_lds16(&Bw[(size_t)(n0 + j * 32 + srow) * K + kt * 64 + scol],
                  &Bs[j * 32 + wid * 8][0]);
    }
    __syncthreads();
#pragma unroll
    for (int kk = 0; kk < 2; ++kk) {
      bf16x8 af[4], bfv[4];
#pragma unroll
      for (int m = 0; m < 4; ++m)
        af[m] = *reinterpret_cast<const bf16x8*>(&As[wm * 64 + m * 16 + l15][kk * 32 + g * 8]);
#pragma unroll
      for (int n = 0; n < 4; ++n)
        bfv[n] = *reinterpret_cast<const bf16x8*>(&Bs[wn * 64 + n * 16 + l15][kk * 32 + g * 8]);
#pragma unroll
      for (int m = 0; m < 4; ++m)
#pragma unroll
        for (int n = 0; n < 4; ++n)
          acc[m][n] = __builtin_amdgcn_mfma_f32_16x16x32_bf16(af[m], bfv[n], acc[m][n], 0, 0, 0);
    }
  }

  if constexpr (EPI == 0) {
#pragma unroll
    for (int n = 0; n < 4; ++n) {
      int col = n0 + wn * 64 + n * 16 + l15;
      float bv = bias[col];
#pragma unroll
      for (int m = 0; m < 4; ++m) {
        int rbase = m0 + wm * 64 + m * 16 + g * 4;
#pragma unroll
        for (int r = 0; r < 4; ++r)
          Cout[(size_t)(rbase + r) * Nn + col] = acc[m][n][r] + bv;
      }
    }
  } else {
    const int which = n0 >> 10;  // block-uniform: 0=q, 1=k, 2=v
    if (which == 2) {
      // v: store TRANSPOSED [bh][d][n], packing 4 consecutive seq (r) per store
#pragma unroll
      for (int m = 0; m < 4; ++m)
#pragma unroll
        for (int n = 0; n < 4; ++n) {
          int col = n0 + wn * 64 + n * 16 + l15;
          int hc = col & 1023;
          int hh = hc >> 6, d = hc & 63;
          int row0 = m0 + wm * 64 + m * 16 + g * 4;
          int seq0 = row0 & (N_ - 1), bb = row0 >> 11;
          ushort4 pk;
          pk.x = f2bf(acc[m][n][0]); pk.y = f2bf(acc[m][n][1]);
          pk.z = f2bf(acc[m][n][2]); pk.w = f2bf(acc[m][n][3]);
          *reinterpret_cast<ushort4*>(
              &vto[(((size_t)bb * H_ + hh) * D_ + d) * N_ + seq0]) = pk;
        }
    } else {
      // q/k: fused RoPE (pair partner is lane^1), q pre-scaled by D^-0.5
      unsigned short* dst = (which == 0) ? qo : ko;
      const float qscale = (which == 0) ? 0.125f : 1.0f;
#pragma unroll
      for (int m = 0; m < 4; ++m)
#pragma unroll
        for (int n = 0; n < 4; ++n)
#pragma unroll
          for (int r = 0; r < 4; ++r) {
            int col = n0 + wn * 64 + n * 16 + l15;
            int row = m0 + wm * 64 + m * 16 + g * 4 + r;
            float val = acc[m][n][r];
            float partner = __shfl_xor(val, 1);
            int hc = col & 1023;
            int hh = hc >> 6, d = hc & 63;
            int seq = row & (N_ - 1), bb = row >> 11;
            float cs = cosT[seq * HALF_ + (d >> 1)];
            float sn = sinT[seq * HALF_ + (d >> 1)];
            float res = (d & 1) ? (partner * sn + val * cs) : (val * cs - partner * sn);
            res *= qscale;
            dst[(((size_t)bb * H_ + hh) * N_ + seq) * D_ + d] = f2bf(res);
          }
    }
  }
}

// ---------------- flash attention, per (b,h), 4 waves x 16 q-rows ----------------
__global__ __launch_bounds__(256) void attn_kernel(
    const unsigned short* __restrict__ q,   // [B*H][N][D] bf16, q pre-scaled
    const unsigned short* __restrict__ k,   // [B*H][N][D]
    const unsigned short* __restrict__ vt,  // [B*H][D][N]  (pre-transposed)
    unsigned short* __restrict__ o) {       // [B*N][C] bf16
  __shared__ __align__(16) unsigned short Kl[64][64];      // [kv][d], swizzled
  __shared__ __align__(16) unsigned short Vl[64][64];      // [d][kv], swizzled
  __shared__ __align__(16) unsigned short Pl[4][16][64];   // per-wave [q][kv], swizzled

  const int tid = threadIdx.x;
  const int lane = tid & 63;
  const int w = tid >> 6;
  const int l15 = lane & 15;
  const int g = lane >> 4;

  // bijective XCD swizzle: 1024 blocks, 128 contiguous (4 heads) per XCD
  const int bid = blockIdx.x;
  const int nat = (bid & 7) * 128 + (bid >> 3);
  const int qt = nat & 31;
  const int bh = nat >> 5;
  const int b = bh >> 4, h = bh & 15;

  const size_t hk = (size_t)bh * N_ * D_;
  const size_t hv = (size_t)bh * D_ * N_;
  const int qrow0 = qt * 64 + w * 16;

  bf16x8 qf[2];
#pragma unroll
  for (int kk = 0; kk < 2; ++kk)
    qf[kk] = *reinterpret_cast<const bf16x8*>(
        &q[hk + (size_t)(qrow0 + l15) * D_ + kk * 32 + g * 8]);

  // staging geometry: 512 u16x8 chunks per tile pair; thread does 2 rows each
  const int prow = tid >> 3;              // 0..31
  const int pchk = tid & 7;               // 16B chunk
  const int swz = (pchk ^ (prow & 7)) * 8;  // (prow+32)&7 == prow&7

  u16x8 kr0, kr1, vr0, vr1;
  auto issue = [&](int t) {
    kr0 = *reinterpret_cast<const u16x8*>(&k[hk + (size_t)(t * 64 + prow) * D_ + pchk * 8]);
    kr1 = *reinterpret_cast<const u16x8*>(&k[hk + (size_t)(t * 64 + prow + 32) * D_ + pchk * 8]);
    vr0 = *reinterpret_cast<const u16x8*>(&vt[hv + (size_t)prow * N_ + t * 64 + pchk * 8]);
    vr1 = *reinterpret_cast<const u16x8*>(&vt[hv + (size_t)(prow + 32) * N_ + t * 64 + pchk * 8]);
  };
  auto commit = [&]() {
    *reinterpret_cast<u16x8*>(&Kl[prow][swz]) = kr0;
    *reinterpret_cast<u16x8*>(&Kl[prow + 32][swz]) = kr1;
    *reinterpret_cast<u16x8*>(&Vl[prow][swz]) = vr0;
    *reinterpret_cast<u16x8*>(&Vl[prow + 32][swz]) = vr1;
  };

  issue(0);
  commit();
  __syncthreads();

  f32x4 accO[4] = {};
  float mrun[4], lrun[4];
#pragma unroll
  for (int r = 0; r < 4; ++r) { mrun[r] = -1e30f; lrun[r] = 0.f; }

  const int NT = N_ / 64;
  for (int t = 0; t < NT; ++t) {
    if (t + 1 < NT) issue(t + 1);  // overlap HBM/L2 latency with compute (T14)

    // S = Q * K^T  (16 x 64 per wave)
    f32x4 sf[4];
    __builtin_amdgcn_s_setprio(1);
#pragma unroll
    for (int f = 0; f < 4; ++f) {
      f32x4 z = {0.f, 0.f, 0.f, 0.f};
      sf[f] = z;
#pragma unroll
      for (int kk = 0; kk < 2; ++kk) {
        bf16x8 kb = *reinterpret_cast<const bf16x8*>(
            &Kl[f * 16 + l15][((kk * 4 + g) ^ (l15 & 7)) * 8]);
        sf[f] = __builtin_amdgcn_mfma_f32_16x16x32_bf16(qf[kk], kb, sf[f], 0, 0, 0);
      }
    }
    __builtin_amdgcn_s_setprio(0);

    // online softmax (rows r in lane group g; kv cols across l15 and f)
    float fac[4];
#pragma unroll
    for (int r = 0; r < 4; ++r) {
      float mx = fmaxf(fmaxf(sf[0][r], sf[1][r]), fmaxf(sf[2][r], sf[3][r]));
      mx = fmaxf(mx, __shfl_xor(mx, 1));
      mx = fmaxf(mx, __shfl_xor(mx, 2));
      mx = fmaxf(mx, __shfl_xor(mx, 4));
      mx = fmaxf(mx, __shfl_xor(mx, 8));
      float mnew = fmaxf(mrun[r], mx);
      fac[r] = __expf(mrun[r] - mnew);
      mrun[r] = mnew;
      float s = 0.f;
#pragma unroll
      for (int f = 0; f < 4; ++f) {
        float p = __expf(sf[f][r] - mnew);
        sf[f][r] = p;
        s += p;
      }
      s += __shfl_xor(s, 1); s += __shfl_xor(s, 2);
      s += __shfl_xor(s, 4); s += __shfl_xor(s, 8);
      lrun[r] = lrun[r] * fac[r] + s;
    }

    // P -> wave-private LDS (swizzled), then read back in A-fragment layout
#pragma unroll
    for (int f = 0; f < 4; ++f)
#pragma unroll
      for (int r = 0; r < 4; ++r) {
        int qq = g * 4 + r;
        Pl[w][qq][((f * 2 + (l15 >> 3)) ^ (qq & 7)) * 8 + (l15 & 7)] = f2bf(sf[f][r]);
      }
    asm volatile("s_waitcnt lgkmcnt(0)" ::: "memory");
    __builtin_amdgcn_sched_barrier(0);

    // rescale O
#pragma unroll
    for (int n = 0; n < 4; ++n)
#pragma unroll
      for (int r = 0; r < 4; ++r) accO[n][r] *= fac[r];

    // O += P * V
    bf16x8 pa[2];
#pragma unroll
    for (int kk = 0; kk < 2; ++kk)
      pa[kk] = *reinterpret_cast<const bf16x8*>(
          &Pl[w][l15][((kk * 4 + g) ^ (l15 & 7)) * 8]);
    __builtin_amdgcn_s_setprio(1);
#pragma unroll
    for (int n = 0; n < 4; ++n)
#pragma unroll
      for (int kk = 0; kk < 2; ++kk) {
        bf16x8 vb = *reinterpret_cast<const bf16x8*>(
            &Vl[n * 16 + l15][((kk * 4 + g) ^ (l15 & 7)) * 8]);
        accO[n] = __builtin_amdgcn_mfma_f32_16x16x32_bf16(pa[kk], vb, accO[n], 0, 0, 0);
      }
    __builtin_amdgcn_s_setprio(0);

    __syncthreads();
    if (t + 1 < NT) commit();
    __syncthreads();
  }

  // epilogue: normalize and store to [b][seq][h*64+d] bf16
#pragma unroll
  for (int n = 0; n < 4; ++n)
#pragma unroll
    for (int r = 0; r < 4; ++r) {
      int qrow = qrow0 + g * 4 + r;
      float val = accO[n][r] / lrun[r];
      o[((size_t)b * N_ + qrow) * C_ + h * 64 + n * 16 + l15] = f2bf(val);
    }
}

extern "C" void kernel_launch(void* const* d_in, const int* in_sizes, int n_in,
                              void* d_out, int out_size, void* d_ws, size_t ws_size,
                              hipStream_t stream) {
  const float* x      = (const float*)d_in[0];
  const float* qkv_w  = (const float*)d_in[1];
  const float* proj_w = (const float*)d_in[2];
  const float* proj_b = (const float*)d_in[3];
  const float* cosT   = (const float*)d_in[4];
  const float* sinT   = (const float*)d_in[5];
  float* out = (float*)d_out;

  // workspace layout (ushort elements), all 16B aligned
  unsigned short* xb     = (unsigned short*)d_ws;                 // 4096*1024
  unsigned short* wqkvb  = xb + (size_t)4096 * 1024;              // 3072*1024
  unsigned short* wprojb = wqkvb + (size_t)3072 * 1024;           // 1024*1024
  unsigned short* qb     = wprojb + (size_t)1024 * 1024;          // 32*2048*64
  unsigned short* kb     = qb + (size_t)32 * 2048 * 64;
  unsigned short* vtb    = kb + (size_t)32 * 2048 * 64;           // [bh][d][n]
  unsigned short* ab     = vtb + (size_t)32 * 2048 * 64;          // 4096*1024

  cast_f32_bf16<<<4096, 256, 0, stream>>>(x, xb, 4096 * 1024 / 4);
  cast_f32_bf16<<<3072, 256, 0, stream>>>(qkv_w, wqkvb, 3072 * 1024 / 4);
  cast_f32_bf16<<<1024, 256, 0, stream>>>(proj_w, wprojb, 1024 * 1024 / 4);

  dim3 g1(4096 / 128, 3072 / 128);
  gemm_bt<1><<<g1, 256, 0, stream>>>(xb, wqkvb, 4096, 3072, 1024,
                                     nullptr, nullptr, qb, kb, vtb, cosT, sinT);

  attn_kernel<<<1024, 256, 0, stream>>>(qb, kb, vtb, ab);

  dim3 g3(4096 / 128, 1024 / 128);
  gemm_bt<0><<<g3, 256, 0, stream>>>(ab, wprojb, 4096, 1024, 1024,
                                     out, proj_b, nullptr, nullptr, nullptr,
                                     nullptr, nullptr);
}

// Round 4
// 152.458 us; speedup vs baseline: 1.6844x; 1.4195x over previous
//
#include <hip/hip_runtime.h>
#include <hip/hip_bf16.h>

#define B_ 2
#define N_ 2048
#define C_ 1024
#define H_ 16
#define D_ 64
#define HALF_ 32

typedef __attribute__((ext_vector_type(8))) __bf16 bf16x8;
typedef __attribute__((ext_vector_type(8))) unsigned short u16x8;
typedef __attribute__((ext_vector_type(4))) float f32x4;
typedef __attribute__((ext_vector_type(16))) float f32x16;

__device__ __forceinline__ unsigned short f2bf(float f) {
  union { float f; unsigned u; } v; v.f = f;
  unsigned r = v.u + 0x7FFFu + ((v.u >> 16) & 1u);
  return (unsigned short)(r >> 16);
}

__device__ __forceinline__ unsigned cvt_pk_bf16(float lo, float hi) {
  unsigned r;
  asm("v_cvt_pk_bf16_f32 %0, %1, %2" : "=v"(r) : "v"(lo), "v"(hi));
  return r;
}

__device__ __forceinline__ void gload_lds16(const void* g, void* l) {
  __builtin_amdgcn_global_load_lds(
      (const __attribute__((address_space(1))) void*)g,
      (__attribute__((address_space(3))) void*)l, 16, 0, 0);
}

// ---------------- cast f32 -> bf16 (vectorized x4) ----------------
__global__ __launch_bounds__(256) void cast_f32_bf16(const float* __restrict__ in,
                                                     unsigned short* __restrict__ out,
                                                     int n4) {
  int i = blockIdx.x * 256 + threadIdx.x;
  if (i >= n4) return;
  float4 v = reinterpret_cast<const float4*>(in)[i];
  ushort4 o;
  o.x = f2bf(v.x); o.y = f2bf(v.y); o.z = f2bf(v.z); o.w = f2bf(v.w);
  reinterpret_cast<ushort4*>(out)[i] = o;
}

// ---------------- GEMM C[M][N] = A[M][K] * Bw[N][K]^T  (m97 structure) -------
template <int EPI>
__global__ __launch_bounds__(256) void gemm_bt(
    const unsigned short* __restrict__ A, const unsigned short* __restrict__ Bw,
    int M, int Nn, int K,
    float* __restrict__ Cout, const float* __restrict__ bias,
    unsigned short* __restrict__ qo, unsigned short* __restrict__ ko,
    unsigned short* __restrict__ vto,
    const float* __restrict__ cosT, const float* __restrict__ sinT) {
  __shared__ __align__(16) unsigned short As[128][64];
  __shared__ __align__(16) unsigned short Bs[128][64];
  const int tid = threadIdx.x;
  const int lane = tid & 63;
  const int wid = tid >> 6;
  const int wm = wid >> 1, wn = wid & 1;
  const int l15 = lane & 15;
  const int g = lane >> 4;
  const int m0 = blockIdx.x * 128;
  const int n0 = blockIdx.y * 128;

  const int srow = wid * 8 + (lane >> 3);
  const int scol = (lane & 7) * 8;

  f32x4 acc[4][4] = {};

  const int nK = K >> 6;
  for (int kt = 0; kt < nK; ++kt) {
    __syncthreads();
#pragma unroll
    for (int j = 0; j < 4; ++j) {
      gload_lds16(&A[(size_t)(m0 + j * 32 + srow) * K + kt * 64 + scol],
                  &As[j * 32 + wid * 8][0]);
      gload_lds16(&Bw[(size_t)(n0 + j * 32 + srow) * K + kt * 64 + scol],
                  &Bs[j * 32 + wid * 8][0]);
    }
    __syncthreads();
#pragma unroll
    for (int kk = 0; kk < 2; ++kk) {
      bf16x8 af[4], bfv[4];
#pragma unroll
      for (int m = 0; m < 4; ++m)
        af[m] = *reinterpret_cast<const bf16x8*>(&As[wm * 64 + m * 16 + l15][kk * 32 + g * 8]);
#pragma unroll
      for (int n = 0; n < 4; ++n)
        bfv[n] = *reinterpret_cast<const bf16x8*>(&Bs[wn * 64 + n * 16 + l15][kk * 32 + g * 8]);
#pragma unroll
      for (int m = 0; m < 4; ++m)
#pragma unroll
        for (int n = 0; n < 4; ++n)
          acc[m][n] = __builtin_amdgcn_mfma_f32_16x16x32_bf16(af[m], bfv[n], acc[m][n], 0, 0, 0);
    }
  }

  if constexpr (EPI == 0) {
#pragma unroll
    for (int n = 0; n < 4; ++n) {
      int col = n0 + wn * 64 + n * 16 + l15;
      float bv = bias[col];
#pragma unroll
      for (int m = 0; m < 4; ++m) {
        int rbase = m0 + wm * 64 + m * 16 + g * 4;
#pragma unroll
        for (int r = 0; r < 4; ++r)
          Cout[(size_t)(rbase + r) * Nn + col] = acc[m][n][r] + bv;
      }
    }
  } else {
    const int which = n0 >> 10;  // block-uniform: 0=q, 1=k, 2=v
    if (which == 2) {
#pragma unroll
      for (int m = 0; m < 4; ++m)
#pragma unroll
        for (int n = 0; n < 4; ++n) {
          int col = n0 + wn * 64 + n * 16 + l15;
          int hc = col & 1023;
          int hh = hc >> 6, d = hc & 63;
          int row0 = m0 + wm * 64 + m * 16 + g * 4;
          int seq0 = row0 & (N_ - 1), bb = row0 >> 11;
          ushort4 pk;
          pk.x = f2bf(acc[m][n][0]); pk.y = f2bf(acc[m][n][1]);
          pk.z = f2bf(acc[m][n][2]); pk.w = f2bf(acc[m][n][3]);
          *reinterpret_cast<ushort4*>(
              &vto[(((size_t)bb * H_ + hh) * D_ + d) * N_ + seq0]) = pk;
        }
    } else {
      unsigned short* dst = (which == 0) ? qo : ko;
      // q gets D^-0.5 AND log2(e) folded in (softmax runs in exp2 domain)
      const float qscale = (which == 0) ? 0.125f * 1.44269504f : 1.0f;
#pragma unroll
      for (int m = 0; m < 4; ++m)
#pragma unroll
        for (int n = 0; n < 4; ++n)
#pragma unroll
          for (int r = 0; r < 4; ++r) {
            int col = n0 + wn * 64 + n * 16 + l15;
            int row = m0 + wm * 64 + m * 16 + g * 4 + r;
            float val = acc[m][n][r];
            float partner = __shfl_xor(val, 1);
            int hc = col & 1023;
            int hh = hc >> 6, d = hc & 63;
            int seq = row & (N_ - 1), bb = row >> 11;
            float cs = cosT[seq * HALF_ + (d >> 1)];
            float sn = sinT[seq * HALF_ + (d >> 1)];
            float res = (d & 1) ? (partner * sn + val * cs) : (val * cs - partner * sn);
            res *= qscale;
            dst[(((size_t)bb * H_ + hh) * N_ + seq) * D_ + d] = f2bf(res);
          }
    }
  }
}

// ---------- flash attention: 8 waves x 32 q-rows, 32x32 MFMA, swapped QK^T ----------
// V LDS tile is stored kv-PERMUTED so the P B-fragment needs NO cross-lane
// exchange: slot (kvc, hi*8+j) <-> kv = kb*32 + 16*(kvc&1) + (j&3) + 8*(j>>2) + 4*hi,
// which is exactly s[kvc>>1][(kvc&1)*8 + j] in this lane's registers.
__global__ __launch_bounds__(512) void attn_kernel(
    const unsigned short* __restrict__ q,   // [B*H][N][D] bf16, q pre-scaled
    const unsigned short* __restrict__ k,   // [B*H][N][D]
    const unsigned short* __restrict__ vt,  // [B*H][D][N]  (pre-transposed)
    unsigned short* __restrict__ o) {       // [B*N][C] bf16
  __shared__ __align__(16) unsigned short Kl[2][64][64];  // [buf][kv][d] swizzled
  __shared__ __align__(16) unsigned short Vl[2][64][64];  // [buf][d][kv-permuted] swizzled

  const int tid = threadIdx.x;
  const int lane = tid & 63;
  const int w = tid >> 6;          // 0..7
  const int l31 = lane & 31;
  const int hi = lane >> 5;

  // head-contiguous XCD swizzle: 256 blocks, 32/XCD -> 4 full heads per XCD L2
  const int bid = blockIdx.x;
  const int nat = (bid & 7) * 32 + (bid >> 3);
  const int qt = nat & 7;
  const int bh = nat >> 3;
  const int b = bh >> 4, h = bh & 15;

  const size_t hk = (size_t)bh * N_ * D_;
  const size_t hv = (size_t)bh * D_ * N_;
  const int qrow = qt * 256 + w * 32 + l31;  // this lane's q (B-frag col)

  // Q fragments: B-operand, col=q=l31, k = d = kt*16 + hi*8 + j
  bf16x8 qf[4];
#pragma unroll
  for (int kt = 0; kt < 4; ++kt)
    qf[kt] = *reinterpret_cast<const bf16x8*>(
        &q[hk + (size_t)qrow * D_ + kt * 16 + hi * 8]);

  // staging: 512 threads x (1 K-chunk + 1 V-chunk) of 16B
  const int prow = tid >> 3;                 // 0..63
  const int pchk = tid & 7;
  const int r7 = prow & 7;
  const int swz = (pchk ^ r7) * 8;
  // V permuted placement: 16B global chunk = kv quads (2*pchk, 2*pchk+1)
  const int vchunk0 = (pchk >> 1) * 2;       // quad 2*pchk  -> chunk vchunk0
  const int vhalf = (pchk & 1) * 4;          //               half = pchk&1
  const int vpos0 = ((vchunk0 ^ r7) << 3) + vhalf;
  const int vpos1 = (((vchunk0 + 1) ^ r7) << 3) + vhalf;

  u16x8 kr, vr;
  auto issue = [&](int t) {
    kr = *reinterpret_cast<const u16x8*>(&k[hk + (size_t)(t * 64 + prow) * D_ + pchk * 8]);
    vr = *reinterpret_cast<const u16x8*>(&vt[hv + (size_t)prow * N_ + t * 64 + pchk * 8]);
  };
  auto commit = [&](int buf) {
    *reinterpret_cast<u16x8*>(&Kl[buf][prow][swz]) = kr;
    union { u16x8 v; ushort4 h[2]; } uv;
    uv.v = vr;
    *reinterpret_cast<ushort4*>(&Vl[buf][prow][vpos0]) = uv.h[0];
    *reinterpret_cast<ushort4*>(&Vl[buf][prow][vpos1]) = uv.h[1];
  };

  issue(0);
  commit(0);
  __syncthreads();

  f32x16 accO[2] = {};
  float mrun = -1e30f, lrun = 0.f;
  const int b7 = l31 & 7;

  const int NT = N_ / 64;
  for (int t = 0; t < NT; ++t) {
    const int cur = t & 1;
    if (t + 1 < NT) issue(t + 1);

    // S^T = K * Q^T : col=q=l31, row kv = (reg&3)+8*(reg>>2)+4*hi (+32*kb)
    f32x16 s[2] = {};
    __builtin_amdgcn_s_setprio(1);
#pragma unroll
    for (int kb = 0; kb < 2; ++kb)
#pragma unroll
      for (int kt = 0; kt < 4; ++kt) {
        bf16x8 kf = *reinterpret_cast<const bf16x8*>(
            &Kl[cur][kb * 32 + l31][(((kt * 2 + hi) ^ b7)) * 8]);
        s[kb] = __builtin_amdgcn_mfma_f32_32x32x16_bf16(kf, qf[kt], s[kb], 0, 0, 0);
      }
    __builtin_amdgcn_s_setprio(0);

    // ---- in-register online softmax, exp2 domain (log2e pre-folded into q) ----
    float mloc[16];
#pragma unroll
    for (int i = 0; i < 16; ++i) mloc[i] = fmaxf(s[0][i], s[1][i]);
#pragma unroll
    for (int st = 8; st > 0; st >>= 1)
#pragma unroll
      for (int i = 0; i < 8; ++i)
        if (i < st) mloc[i] = fmaxf(mloc[i], mloc[i + st]);
    float mx;
    {
      unsigned ua = __float_as_uint(mloc[0]), ub = ua;
      auto r = __builtin_amdgcn_permlane32_swap(ua, ub, false, false);
      mx = fmaxf(__uint_as_float(r[0]), __uint_as_float(r[1]));
    }

    float mnew = fmaxf(mrun, mx);
    if (!__all(mx - mrun <= 8.0f)) {   // T13 defer-max (log2 units: P <= 2^8)
      float fac = __builtin_exp2f(mrun - mnew);
      lrun *= fac;
#pragma unroll
      for (int db = 0; db < 2; ++db)
#pragma unroll
        for (int i = 0; i < 16; ++i) accO[db][i] *= fac;
      mrun = mnew;
    }

#pragma unroll
    for (int kb = 0; kb < 2; ++kb)
#pragma unroll
      for (int i = 0; i < 16; ++i) s[kb][i] = __builtin_exp2f(s[kb][i] - mrun);

    float sloc[16];
#pragma unroll
    for (int i = 0; i < 16; ++i) sloc[i] = s[0][i] + s[1][i];
#pragma unroll
    for (int st = 8; st > 0; st >>= 1)
#pragma unroll
      for (int i = 0; i < 8; ++i)
        if (i < st) sloc[i] += sloc[i + st];
    {
      unsigned ua = __float_as_uint(sloc[0]), ub = ua;
      auto r = __builtin_amdgcn_permlane32_swap(ua, ub, false, false);
      lrun += __uint_as_float(r[0]) + __uint_as_float(r[1]);
    }

    // ---- P -> bf16 B-fragments fully in-lane (V kv-permutation matches) ----
    bf16x8 PA[4];
#pragma unroll
    for (int kvc = 0; kvc < 4; ++kvc) {
      const int kb = kvc >> 1, base = (kvc & 1) * 8;
      union { unsigned u[4]; bf16x8 v; } pa;
#pragma unroll
      for (int wd = 0; wd < 4; ++wd)
        pa.u[wd] = cvt_pk_bf16(s[kb][base + 2 * wd], s[kb][base + 2 * wd + 1]);
      PA[kvc] = pa.v;
    }

    // ---- O^T += V^T * P : A row = d, k = kv-permuted slots ----
    __builtin_amdgcn_s_setprio(1);
#pragma unroll
    for (int db = 0; db < 2; ++db)
#pragma unroll
      for (int kvc = 0; kvc < 4; ++kvc) {
        bf16x8 vf = *reinterpret_cast<const bf16x8*>(
            &Vl[cur][db * 32 + l31][(((kvc * 2 + hi) ^ b7)) * 8]);
        accO[db] = __builtin_amdgcn_mfma_f32_32x32x16_bf16(vf, PA[kvc], accO[db], 0, 0, 0);
      }
    __builtin_amdgcn_s_setprio(0);

    if (t + 1 < NT) commit(cur ^ 1);
    __syncthreads();
  }

  // epilogue: O[q][d] = accO^T / lrun ; store to [b][seq][h*64+d]
  float rl = 1.0f / lrun;
  const size_t obase = ((size_t)b * N_ + qrow) * C_ + h * 64;
#pragma unroll
  for (int db = 0; db < 2; ++db)
#pragma unroll
    for (int rg = 0; rg < 4; ++rg) {
      ushort4 pk;
      pk.x = f2bf(accO[db][rg * 4 + 0] * rl);
      pk.y = f2bf(accO[db][rg * 4 + 1] * rl);
      pk.z = f2bf(accO[db][rg * 4 + 2] * rl);
      pk.w = f2bf(accO[db][rg * 4 + 3] * rl);
      *reinterpret_cast<ushort4*>(&o[obase + db * 32 + rg * 8 + hi * 4]) = pk;
    }
}

extern "C" void kernel_launch(void* const* d_in, const int* in_sizes, int n_in,
                              void* d_out, int out_size, void* d_ws, size_t ws_size,
                              hipStream_t stream) {
  const float* x      = (const float*)d_in[0];
  const float* qkv_w  = (const float*)d_in[1];
  const float* proj_w = (const float*)d_in[2];
  const float* proj_b = (const float*)d_in[3];
  const float* cosT   = (const float*)d_in[4];
  const float* sinT   = (const float*)d_in[5];
  float* out = (float*)d_out;

  unsigned short* xb     = (unsigned short*)d_ws;                 // 4096*1024
  unsigned short* wqkvb  = xb + (size_t)4096 * 1024;              // 3072*1024
  unsigned short* wprojb = wqkvb + (size_t)3072 * 1024;           // 1024*1024
  unsigned short* qb     = wprojb + (size_t)1024 * 1024;          // 32*2048*64
  unsigned short* kb     = qb + (size_t)32 * 2048 * 64;
  unsigned short* vtb    = kb + (size_t)32 * 2048 * 64;           // [bh][d][n]
  unsigned short* ab     = vtb + (size_t)32 * 2048 * 64;          // 4096*1024

  cast_f32_bf16<<<4096, 256, 0, stream>>>(x, xb, 4096 * 1024 / 4);
  cast_f32_bf16<<<3072, 256, 0, stream>>>(qkv_w, wqkvb, 3072 * 1024 / 4);
  cast_f32_bf16<<<1024, 256, 0, stream>>>(proj_w, wprojb, 1024 * 1024 / 4);

  dim3 g1(4096 / 128, 3072 / 128);
  gemm_bt<1><<<g1, 256, 0, stream>>>(xb, wqkvb, 4096, 3072, 1024,
                                     nullptr, nullptr, qb, kb, vtb, cosT, sinT);

  attn_kernel<<<256, 512, 0, stream>>>(qb, kb, vtb, ab);

  dim3 g3(4096 / 128, 1024 / 128);
  gemm_bt<0><<<g3, 256, 0, stream>>>(ab, wprojb, 4096, 1024, 1024,
                                     out, proj_b, nullptr, nullptr, nullptr,
                                     nullptr, nullptr);
}